// Round 5
// baseline (368.636 us; speedup 1.0000x reference)
//
#include <hip/hip_runtime.h>
#include <math.h>

#define NB      512
#define NELEC   30
#define NATOMS  10
#define NNEN    40      // en graph nodes: 30 electrons + 10 atoms
#define FEAT    64
#define KRBF    64
#define BLOCK   1024    // 16 waves: waves 0-7 = feature-half 0, waves 8-15 = half 1
#define NWAVES  (BLOCK/64)
#define NPEE    435     // unique elec-elec pairs
#define NPEN    300     // unique elec-nuc pairs
#define TILE    32      // feature half per thread (32 persistent VGPRs, fits 64-reg budget)
#define TPAD    33      // tile row stride (+1): lanes hit banks (p+ff)%32, 2-way = free

// ---------------- LDS layouts (in floats) ----------------
#define EE_H     96
#define EE_AGG   (EE_H + NELEC*FEAT)
#define EE_FT    (EE_AGG + NELEC*FEAT)
#define EE_TOTAL (EE_FT + NPEE*TPAD)            // 18291 floats = 73164 B -> 2 blocks/CU
#define EN_H     96
#define EN_AGG   (EN_H + NNEN*FEAT)
#define EN_FT    (EN_AGG + NNEN*FEAT)
#define EN_TOTAL (EN_FT + NPEN*TPAD)            // 15116 floats = 60464 B -> 2 blocks/CU

// 2 blocks/CU * 16 waves = 32 waves/CU = 8 waves/EU -> 64-VGPR budget.
// Per-thread persistent state is now only 32 regs, so 64 is sufficient
// (R2-R4: 64 persistent regs under a 64-reg budget -> 50+ MB scratch spill).
#define KERNEL_ATTRS __attribute__((amdgpu_flat_work_group_size(BLOCK, BLOCK), \
                                    amdgpu_waves_per_eu(8, 8)))

// triangular pair index base for row i (i<j pairs of 30 electrons)
__device__ __forceinline__ int ee_base(int i) { return 29*i - ((i*(i-1))>>1); }

// ==========================================================================
// elec-elec GNN: one block per batch. Writes partial log-Jastrow (double).
// Thread (p, hf) computes filter features [hf*32, hf*32+32) of pair p; both
// halves recompute the same distance (identical bits). FP op sequences are
// bit-identical to the R1 passing kernel.
// ==========================================================================
__global__ KERNEL_ATTRS
void ee_kernel(const float* __restrict__ pos,
               const float* __restrict__ emb,
               const float* __restrict__ wf,
               const float* __restrict__ bf,
               const float* __restrict__ wl,
               const float* __restrict__ bl,
               const float* __restrict__ wr,
               const float* __restrict__ br,
               const int*   __restrict__ types,
               double*      __restrict__ kout)
{
    extern __shared__ float sm[];
    float* xyz  = sm;           // [96]
    float* hS   = sm + EE_H;    // [30][64]
    float* aggS = sm + EE_AGG;  // [30][64]
    float* fT   = sm + EE_FT;   // [435][33] feature-half tile

    const int tid  = threadIdx.x;
    const int b    = blockIdx.x;
    const int lane = tid & 63;
    const int w    = tid >> 6;

    // stage positions; init h = emb[types]
    for (int idx = tid; idx < NELEC*3; idx += BLOCK) xyz[idx] = pos[b*NELEC*3 + idx];
    for (int idx = tid; idx < NELEC*FEAT; idx += BLOCK) {
        int n = idx >> 6, f = idx & 63;
        hS[idx] = emb[types[n]*FEAT + f];
    }
    __syncthreads();

    // ---- filter GEMM: thread = (pair, feature-half); 32 regs/thread ----
    const int p  = ((tid & 511) < NPEE) ? (tid & 511) : (NPEE - 1);
    const int hf = __builtin_amdgcn_readfirstlane(tid >> 9);  // wave-uniform half
    float facc[TILE];
    {
        int i = 0, rem = p;
        while (rem >= NELEC - 1 - i) { rem -= NELEC - 1 - i; ++i; }
        const int j = i + 1 + rem;
        const float dx = xyz[3*i+0] - xyz[3*j+0];
        const float dy = xyz[3*i+1] - xyz[3*j+1];
        const float dz = xyz[3*i+2] - xyz[3*j+2];
        const float dd = sqrtf(dx*dx + dy*dy + dz*dz);

        const float* bfh = bf + hf*TILE;                 // wave-uniform -> s_load
        #pragma unroll
        for (int f = 0; f < TILE; ++f) facc[f] = bfh[f];
        #pragma unroll 2
        for (int k = 0; k < KRBF; ++k) {
            const float ck = (float)((double)k * (8.0/63.0));
            const float t  = dd - ck;
            const float rk = expf(-t*t);
            const float* wrow = wf + k*FEAT + hf*TILE;   // wave-uniform row
            #pragma unroll
            for (int f = 0; f < TILE; ++f) facc[f] = fmaf(rk, wrow[f], facc[f]);
        }
        #pragma unroll
        for (int f = 0; f < TILE; ++f) facc[f] = tanhf(facc[f]);
    }

    // ---- interaction layers ----
    for (int l = 0; l < 2; ++l) {
        const float* wlL = wl + l*FEAT*FEAT;
        const float* blL = bl + l*FEAT;

        for (int t = 0; t < 2; ++t) {
            __syncthreads();   // protect fT from previous tile's readers
            if (hf == t) {
                #pragma unroll
                for (int ff = 0; ff < TILE; ++ff)
                    fT[p*TPAD + ff] = facc[ff];          // static reg indices
            }
            __syncthreads();

            // agg[i][t*32+ff] = sum_{j!=i, j asc} h[j][f] * filt[p(i,j)][f]
            if (tid < NELEC*TILE) {                      // 960 items, one pass
                const int i  = tid >> 5;
                const int ff = tid & 31;
                const int f  = t*TILE + ff;
                float a = 0.f;
                #pragma unroll
                for (int j = 0; j < NELEC; ++j) {
                    if (j != i) {
                        int pp = (j < i) ? (ee_base(j) + (i - j - 1))
                                         : (ee_base(i) + (j - i - 1));
                        a = fmaf(hS[j*FEAT + f], fT[pp*TPAD + ff], a);
                    }
                }
                aggS[i*FEAT + f] = a;
            }
        }
        __syncthreads();

        // h += tanh(agg @ wl + bl)   (lane = feature, wave-strided nodes)
        for (int i = w; i < NELEC; i += NWAVES) {
            float a2 = 0.f;
            const float4* arow = reinterpret_cast<const float4*>(aggS + i*FEAT);
            #pragma unroll
            for (int k = 0; k < FEAT/4; ++k) {
                float4 av = arow[k];                      // broadcast b128
                a2 = fmaf(av.x, wlL[(4*k+0)*FEAT + lane], a2);
                a2 = fmaf(av.y, wlL[(4*k+1)*FEAT + lane], a2);
                a2 = fmaf(av.z, wlL[(4*k+2)*FEAT + lane], a2);
                a2 = fmaf(av.w, wlL[(4*k+3)*FEAT + lane], a2);
            }
            hS[i*FEAT + lane] += tanhf(a2 + blL[lane]);
        }
        __syncthreads();
    }

    // ---- readout: (sum_n h[n]) . wr + br   (f64 tail) ----
    if (w == 0) {
        float s = 0.f;
        #pragma unroll
        for (int n = 0; n < NELEC; ++n) s += hS[n*FEAT + lane];
        double dv = (double)s * (double)wr[lane];
        #pragma unroll
        for (int o = 32; o > 0; o >>= 1) dv += __shfl_xor(dv, o, 64);
        if (lane == 0) kout[b] = dv + (double)br[0];
    }
}

// ==========================================================================
// elec-nuc GNN + final combine: out[b] = exp(k_ee + k_en)
// ==========================================================================
__global__ KERNEL_ATTRS
void en_kernel(const float* __restrict__ pos,
               const float* __restrict__ atoms,
               const float* __restrict__ emb,
               const float* __restrict__ wf,
               const float* __restrict__ bf,
               const float* __restrict__ wl,
               const float* __restrict__ bl,
               const float* __restrict__ wr,
               const float* __restrict__ br,
               const int*   __restrict__ types,
               const double* __restrict__ kin,
               float*       __restrict__ out)
{
    extern __shared__ float sm[];
    float* xyz  = sm;           // [96]
    float* hS   = sm + EN_H;    // [40][64]
    float* aggS = sm + EN_AGG;  // [40][64]
    float* fT   = sm + EN_FT;   // [300][33]

    const int tid  = threadIdx.x;
    const int b    = blockIdx.x;
    const int lane = tid & 63;
    const int w    = tid >> 6;

    for (int idx = tid; idx < NELEC*3; idx += BLOCK) xyz[idx] = pos[b*NELEC*3 + idx];
    for (int idx = tid; idx < NNEN*FEAT; idx += BLOCK) {
        int n = idx >> 6, f = idx & 63;
        hS[idx] = emb[types[n]*FEAT + f];
    }
    __syncthreads();

    // ---- filter GEMM: pair q = a*30 + e (atom-major); thread = (pair, half) ----
    const int p  = ((tid & 511) < NPEN) ? (tid & 511) : (NPEN - 1);
    const int hf = __builtin_amdgcn_readfirstlane(tid >> 9);
    float facc[TILE];
    {
        const int a = p / NELEC;
        const int e = p - a*NELEC;
        const float dx = xyz[3*e+0] - atoms[3*a+0];
        const float dy = xyz[3*e+1] - atoms[3*a+1];
        const float dz = xyz[3*e+2] - atoms[3*a+2];
        const float dd = sqrtf(dx*dx + dy*dy + dz*dz);

        const float* bfh = bf + hf*TILE;
        #pragma unroll
        for (int f = 0; f < TILE; ++f) facc[f] = bfh[f];
        #pragma unroll 2
        for (int k = 0; k < KRBF; ++k) {
            const float ck = (float)((double)k * (8.0/63.0));
            const float t  = dd - ck;
            const float rk = expf(-t*t);
            const float* wrow = wf + k*FEAT + hf*TILE;
            #pragma unroll
            for (int f = 0; f < TILE; ++f) facc[f] = fmaf(rk, wrow[f], facc[f]);
        }
        #pragma unroll
        for (int f = 0; f < TILE; ++f) facc[f] = tanhf(facc[f]);
    }

    for (int l = 0; l < 2; ++l) {
        const float* wlL = wl + l*FEAT*FEAT;
        const float* blL = bl + l*FEAT;

        for (int t = 0; t < 2; ++t) {
            __syncthreads();
            if (hf == t) {
                #pragma unroll
                for (int ff = 0; ff < TILE; ++ff)
                    fT[p*TPAD + ff] = facc[ff];
            }
            __syncthreads();

            // bipartite messages: 40 nodes x 32 feats = 1280 items
            for (int idx = tid; idx < NNEN*TILE; idx += BLOCK) {
                const int n  = idx >> 5;
                const int ff = idx & 31;
                const int f  = t*TILE + ff;
                float a = 0.f;
                if (n < NELEC) {            // electron node: atoms ascending
                    #pragma unroll
                    for (int at = 0; at < NATOMS; ++at)
                        a = fmaf(hS[(NELEC+at)*FEAT + f],
                                 fT[(at*NELEC + n)*TPAD + ff], a);
                } else {                    // atom node: electrons ascending
                    const int at = n - NELEC;
                    #pragma unroll
                    for (int e2 = 0; e2 < NELEC; ++e2)
                        a = fmaf(hS[e2*FEAT + f],
                                 fT[(at*NELEC + e2)*TPAD + ff], a);
                }
                aggS[n*FEAT + f] = a;
            }
        }
        __syncthreads();

        for (int n = w; n < NNEN; n += NWAVES) {
            float a2 = 0.f;
            const float4* arow = reinterpret_cast<const float4*>(aggS + n*FEAT);
            #pragma unroll
            for (int k = 0; k < FEAT/4; ++k) {
                float4 av = arow[k];
                a2 = fmaf(av.x, wlL[(4*k+0)*FEAT + lane], a2);
                a2 = fmaf(av.y, wlL[(4*k+1)*FEAT + lane], a2);
                a2 = fmaf(av.z, wlL[(4*k+2)*FEAT + lane], a2);
                a2 = fmaf(av.w, wlL[(4*k+3)*FEAT + lane], a2);
            }
            hS[n*FEAT + lane] += tanhf(a2 + blL[lane]);
        }
        __syncthreads();
    }

    if (w == 0) {
        float s = 0.f;
        #pragma unroll
        for (int n = 0; n < NNEN; ++n) s += hS[n*FEAT + lane];
        double dv = (double)s * (double)wr[lane];
        #pragma unroll
        for (int o = 32; o > 0; o >>= 1) dv += __shfl_xor(dv, o, 64);
        if (lane == 0) out[b] = (float)exp(dv + (double)br[0] + kin[b]);
    }
}

// ==========================================================================
extern "C" void kernel_launch(void* const* d_in, const int* in_sizes, int n_in,
                              void* d_out, int out_size, void* d_ws, size_t ws_size,
                              hipStream_t stream) {
    const float* pos    = (const float*)d_in[0];
    const float* atoms  = (const float*)d_in[1];
    const float* emb_ee = (const float*)d_in[2];
    const float* wf_ee  = (const float*)d_in[3];
    const float* bf_ee  = (const float*)d_in[4];
    const float* wl_ee  = (const float*)d_in[5];
    const float* bl_ee  = (const float*)d_in[6];
    const float* wr_ee  = (const float*)d_in[7];
    const float* br_ee  = (const float*)d_in[8];
    const float* emb_en = (const float*)d_in[9];
    const float* wf_en  = (const float*)d_in[10];
    const float* bf_en  = (const float*)d_in[11];
    const float* wl_en  = (const float*)d_in[12];
    const float* bl_en  = (const float*)d_in[13];
    const float* wr_en  = (const float*)d_in[14];
    const float* br_en  = (const float*)d_in[15];
    const int*   ee_ty  = (const int*)d_in[18];
    const int*   en_ty  = (const int*)d_in[21];

    double* kws = (double*)d_ws;       // [512] partial log-Jastrow from ee
    float*  out = (float*)d_out;       // [512]

    (void)hipFuncSetAttribute((const void*)ee_kernel,
            hipFuncAttributeMaxDynamicSharedMemorySize, EE_TOTAL*(int)sizeof(float));
    (void)hipFuncSetAttribute((const void*)en_kernel,
            hipFuncAttributeMaxDynamicSharedMemorySize, EN_TOTAL*(int)sizeof(float));

    ee_kernel<<<NB, BLOCK, EE_TOTAL*sizeof(float), stream>>>(
        pos, emb_ee, wf_ee, bf_ee, wl_ee, bl_ee, wr_ee, br_ee, ee_ty, kws);
    en_kernel<<<NB, BLOCK, EN_TOTAL*sizeof(float), stream>>>(
        pos, atoms, emb_en, wf_en, bf_en, wl_en, bl_en, wr_en, br_en, en_ty, kws, out);
}

// Round 6
// 246.782 us; speedup vs baseline: 1.4938x; 1.4938x over previous
//
#include <hip/hip_runtime.h>
#include <math.h>

#define NB      512
#define NELEC   30
#define NATOMS  10
#define NNEN    40      // en graph nodes: 30 electrons + 10 atoms
#define FEAT    64
#define KRBF    64
#define BLOCK   1024    // 16 waves/CU (1 block/CU by LDS) -- R1 had only 8
#define NWAVES  (BLOCK/64)
#define NPEE    435     // unique elec-elec pairs
#define NPEN    300     // unique elec-nuc pairs
#define HTILE   32      // feature-half per thread in filter phase (local acc only!)
#define FPAD    65      // filt row stride: banks (p+f)%32, 2-way on 64 lanes = free

// ---------------- LDS layouts (in floats) ----------------
// ee: xyz[96] | h[30*64] | agg[30*64] | filt[435*65]
#define EE_H     96
#define EE_AGG   (EE_H + NELEC*FEAT)
#define EE_FILT  (EE_AGG + NELEC*FEAT)
#define EE_TOTAL (EE_FILT + NPEE*FPAD)          // 32211 floats = 128844 B -> 1 block/CU
// en: xyz[96] | h[40*64] | agg[40*64] | filt[300*65]
#define EN_H     96
#define EN_AGG   (EN_H + NNEN*FEAT)
#define EN_FILT  (EN_AGG + NNEN*FEAT)
#define EN_TOTAL (EN_FILT + NPEN*FPAD)          // 24716 floats = 98864 B  -> 1 block/CU

// NO waves_per_eu / launch_bounds occupancy hints: R3-R5 showed they either
// do nothing or shrink the budget and force spill. R1's spill-free pattern:
// accumulators are LOCAL to the filter scope and stored to LDS immediately,
// so the allocator can restructure freely under its default 64-VGPR target.
#define KERNEL_ATTRS __attribute__((amdgpu_flat_work_group_size(BLOCK, BLOCK)))

// triangular pair index base for row i (i<j pairs of 30 electrons)
__device__ __forceinline__ int ee_base(int i) { return 29*i - ((i*(i-1))>>1); }

// ==========================================================================
// elec-elec GNN: one block per batch. Writes partial log-Jastrow (double).
// Filter phase: thread = (pair, feature-half); acc[32] local, -> LDS at once.
// FP op sequences bit-identical to the R1 passing kernel.
// ==========================================================================
__global__ KERNEL_ATTRS
void ee_kernel(const float* __restrict__ pos,
               const float* __restrict__ emb,
               const float* __restrict__ wf,
               const float* __restrict__ bf,
               const float* __restrict__ wl,
               const float* __restrict__ bl,
               const float* __restrict__ wr,
               const float* __restrict__ br,
               const int*   __restrict__ types,
               double*      __restrict__ kout)
{
    extern __shared__ float sm[];
    float* xyz  = sm;            // [96]
    float* hS   = sm + EE_H;     // [30][64]
    float* aggS = sm + EE_AGG;   // [30][64]
    float* fS   = sm + EE_FILT;  // [435][65]

    const int tid  = threadIdx.x;
    const int b    = blockIdx.x;
    const int lane = tid & 63;
    const int w    = tid >> 6;

    // stage positions; init h = emb[types]
    for (int idx = tid; idx < NELEC*3; idx += BLOCK) xyz[idx] = pos[b*NELEC*3 + idx];
    for (int idx = tid; idx < NELEC*FEAT; idx += BLOCK) {
        int n = idx >> 6, f = idx & 63;
        hS[idx] = emb[types[n]*FEAT + f];
    }
    __syncthreads();

    // ---- filter GEMM: thread = (pair, half); acc local, stored immediately ----
    {
        const int p  = ((tid & 511) < NPEE) ? (tid & 511) : (NPEE - 1);
        const int hf = __builtin_amdgcn_readfirstlane(tid >> 9);  // wave-uniform
        int i = 0, rem = p;
        while (rem >= NELEC - 1 - i) { rem -= NELEC - 1 - i; ++i; }
        const int j = i + 1 + rem;
        const float dx = xyz[3*i+0] - xyz[3*j+0];
        const float dy = xyz[3*i+1] - xyz[3*j+1];
        const float dz = xyz[3*i+2] - xyz[3*j+2];
        const float dd = sqrtf(dx*dx + dy*dy + dz*dz);

        float acc[HTILE];
        const float* bfh = bf + hf*HTILE;                // wave-uniform -> s_load
        #pragma unroll
        for (int f = 0; f < HTILE; ++f) acc[f] = bfh[f];
        #pragma unroll 2
        for (int k = 0; k < KRBF; ++k) {
            const float ck = (float)((double)k * (8.0/63.0));
            const float t  = dd - ck;
            const float rk = expf(-t*t);
            const float* wrow = wf + k*FEAT + hf*HTILE;  // wave-uniform row
            #pragma unroll
            for (int f = 0; f < HTILE; ++f) acc[f] = fmaf(rk, wrow[f], acc[f]);
        }
        #pragma unroll
        for (int f = 0; f < HTILE; ++f)
            fS[p*FPAD + hf*HTILE + f] = tanhf(acc[f]);   // dup pairs: same bits
    }
    __syncthreads();

    // ---- interaction layers: 2 barriers per layer ----
    for (int l = 0; l < 2; ++l) {
        const float* wlL = wl + l*FEAT*FEAT;
        const float* blL = bl + l*FEAT;

        // messages: (i,f) items = 1920, two passes of 1024
        #pragma unroll
        for (int pass = 0; pass < 2; ++pass) {
            const int idx = tid + pass*BLOCK;
            if (idx < NELEC*FEAT) {
                const int i = idx >> 6;
                const int f = idx & 63;
                float a = 0.f;
                #pragma unroll
                for (int j = 0; j < NELEC; ++j) {
                    if (j != i) {
                        int pp = (j < i) ? (ee_base(j) + (i - j - 1))
                                         : (ee_base(i) + (j - i - 1));
                        a = fmaf(hS[j*FEAT + f], fS[pp*FPAD + f], a);
                    }
                }
                aggS[i*FEAT + f] = a;
            }
        }
        __syncthreads();

        // h += tanh(agg @ wl + bl)   (lane = feature, wave-strided nodes)
        for (int i = w; i < NELEC; i += NWAVES) {
            float a2 = 0.f;
            const float4* arow = reinterpret_cast<const float4*>(aggS + i*FEAT);
            #pragma unroll
            for (int k = 0; k < FEAT/4; ++k) {
                float4 av = arow[k];                      // broadcast b128
                a2 = fmaf(av.x, wlL[(4*k+0)*FEAT + lane], a2);
                a2 = fmaf(av.y, wlL[(4*k+1)*FEAT + lane], a2);
                a2 = fmaf(av.z, wlL[(4*k+2)*FEAT + lane], a2);
                a2 = fmaf(av.w, wlL[(4*k+3)*FEAT + lane], a2);
            }
            hS[i*FEAT + lane] += tanhf(a2 + blL[lane]);
        }
        __syncthreads();
    }

    // ---- readout: (sum_n h[n]) . wr + br   (f64 tail) ----
    if (w == 0) {
        float s = 0.f;
        #pragma unroll
        for (int n = 0; n < NELEC; ++n) s += hS[n*FEAT + lane];
        double dv = (double)s * (double)wr[lane];
        #pragma unroll
        for (int o = 32; o > 0; o >>= 1) dv += __shfl_xor(dv, o, 64);
        if (lane == 0) kout[b] = dv + (double)br[0];
    }
}

// ==========================================================================
// elec-nuc GNN + final combine: out[b] = exp(k_ee + k_en)
// ==========================================================================
__global__ KERNEL_ATTRS
void en_kernel(const float* __restrict__ pos,
               const float* __restrict__ atoms,
               const float* __restrict__ emb,
               const float* __restrict__ wf,
               const float* __restrict__ bf,
               const float* __restrict__ wl,
               const float* __restrict__ bl,
               const float* __restrict__ wr,
               const float* __restrict__ br,
               const int*   __restrict__ types,
               const double* __restrict__ kin,
               float*       __restrict__ out)
{
    extern __shared__ float sm[];
    float* xyz  = sm;            // [96]
    float* hS   = sm + EN_H;     // [40][64]
    float* aggS = sm + EN_AGG;   // [40][64]
    float* fS   = sm + EN_FILT;  // [300][65]

    const int tid  = threadIdx.x;
    const int b    = blockIdx.x;
    const int lane = tid & 63;
    const int w    = tid >> 6;

    for (int idx = tid; idx < NELEC*3; idx += BLOCK) xyz[idx] = pos[b*NELEC*3 + idx];
    for (int idx = tid; idx < NNEN*FEAT; idx += BLOCK) {
        int n = idx >> 6, f = idx & 63;
        hS[idx] = emb[types[n]*FEAT + f];
    }
    __syncthreads();

    // ---- filter GEMM: pair q = a*30 + e (atom-major); thread = (pair, half) ----
    {
        const int p  = ((tid & 511) < NPEN) ? (tid & 511) : (NPEN - 1);
        const int hf = __builtin_amdgcn_readfirstlane(tid >> 9);
        const int a  = p / NELEC;
        const int e  = p - a*NELEC;
        const float dx = xyz[3*e+0] - atoms[3*a+0];
        const float dy = xyz[3*e+1] - atoms[3*a+1];
        const float dz = xyz[3*e+2] - atoms[3*a+2];
        const float dd = sqrtf(dx*dx + dy*dy + dz*dz);

        float acc[HTILE];
        const float* bfh = bf + hf*HTILE;
        #pragma unroll
        for (int f = 0; f < HTILE; ++f) acc[f] = bfh[f];
        #pragma unroll 2
        for (int k = 0; k < KRBF; ++k) {
            const float ck = (float)((double)k * (8.0/63.0));
            const float t  = dd - ck;
            const float rk = expf(-t*t);
            const float* wrow = wf + k*FEAT + hf*HTILE;
            #pragma unroll
            for (int f = 0; f < HTILE; ++f) acc[f] = fmaf(rk, wrow[f], acc[f]);
        }
        #pragma unroll
        for (int f = 0; f < HTILE; ++f)
            fS[p*FPAD + hf*HTILE + f] = tanhf(acc[f]);
    }
    __syncthreads();

    for (int l = 0; l < 2; ++l) {
        const float* wlL = wl + l*FEAT*FEAT;
        const float* blL = bl + l*FEAT;

        // bipartite messages: (n,f) items = 2560, three passes
        #pragma unroll
        for (int pass = 0; pass < 3; ++pass) {
            const int idx = tid + pass*BLOCK;
            if (idx < NNEN*FEAT) {
                const int n = idx >> 6;
                const int f = idx & 63;
                float a = 0.f;
                if (n < NELEC) {            // electron node: atoms ascending
                    #pragma unroll
                    for (int at = 0; at < NATOMS; ++at)
                        a = fmaf(hS[(NELEC+at)*FEAT + f],
                                 fS[(at*NELEC + n)*FPAD + f], a);
                } else {                    // atom node: electrons ascending
                    const int at = n - NELEC;
                    #pragma unroll
                    for (int e2 = 0; e2 < NELEC; ++e2)
                        a = fmaf(hS[e2*FEAT + f],
                                 fS[(at*NELEC + e2)*FPAD + f], a);
                }
                aggS[n*FEAT + f] = a;
            }
        }
        __syncthreads();

        for (int n = w; n < NNEN; n += NWAVES) {
            float a2 = 0.f;
            const float4* arow = reinterpret_cast<const float4*>(aggS + n*FEAT);
            #pragma unroll
            for (int k = 0; k < FEAT/4; ++k) {
                float4 av = arow[k];
                a2 = fmaf(av.x, wlL[(4*k+0)*FEAT + lane], a2);
                a2 = fmaf(av.y, wlL[(4*k+1)*FEAT + lane], a2);
                a2 = fmaf(av.z, wlL[(4*k+2)*FEAT + lane], a2);
                a2 = fmaf(av.w, wlL[(4*k+3)*FEAT + lane], a2);
            }
            hS[n*FEAT + lane] += tanhf(a2 + blL[lane]);
        }
        __syncthreads();
    }

    if (w == 0) {
        float s = 0.f;
        #pragma unroll
        for (int n = 0; n < NNEN; ++n) s += hS[n*FEAT + lane];
        double dv = (double)s * (double)wr[lane];
        #pragma unroll
        for (int o = 32; o > 0; o >>= 1) dv += __shfl_xor(dv, o, 64);
        if (lane == 0) out[b] = (float)exp(dv + (double)br[0] + kin[b]);
    }
}

// ==========================================================================
extern "C" void kernel_launch(void* const* d_in, const int* in_sizes, int n_in,
                              void* d_out, int out_size, void* d_ws, size_t ws_size,
                              hipStream_t stream) {
    const float* pos    = (const float*)d_in[0];
    const float* atoms  = (const float*)d_in[1];
    const float* emb_ee = (const float*)d_in[2];
    const float* wf_ee  = (const float*)d_in[3];
    const float* bf_ee  = (const float*)d_in[4];
    const float* wl_ee  = (const float*)d_in[5];
    const float* bl_ee  = (const float*)d_in[6];
    const float* wr_ee  = (const float*)d_in[7];
    const float* br_ee  = (const float*)d_in[8];
    const float* emb_en = (const float*)d_in[9];
    const float* wf_en  = (const float*)d_in[10];
    const float* bf_en  = (const float*)d_in[11];
    const float* wl_en  = (const float*)d_in[12];
    const float* bl_en  = (const float*)d_in[13];
    const float* wr_en  = (const float*)d_in[14];
    const float* br_en  = (const float*)d_in[15];
    const int*   ee_ty  = (const int*)d_in[18];
    const int*   en_ty  = (const int*)d_in[21];

    double* kws = (double*)d_ws;       // [512] partial log-Jastrow from ee
    float*  out = (float*)d_out;       // [512]

    (void)hipFuncSetAttribute((const void*)ee_kernel,
            hipFuncAttributeMaxDynamicSharedMemorySize, EE_TOTAL*(int)sizeof(float));
    (void)hipFuncSetAttribute((const void*)en_kernel,
            hipFuncAttributeMaxDynamicSharedMemorySize, EN_TOTAL*(int)sizeof(float));

    ee_kernel<<<NB, BLOCK, EE_TOTAL*sizeof(float), stream>>>(
        pos, emb_ee, wf_ee, bf_ee, wl_ee, bl_ee, wr_ee, br_ee, ee_ty, kws);
    en_kernel<<<NB, BLOCK, EN_TOTAL*sizeof(float), stream>>>(
        pos, atoms, emb_en, wf_en, bf_en, wl_en, bl_en, wr_en, br_en, en_ty, kws, out);
}